// Round 6
// baseline (14629.922 us; speedup 1.0000x reference)
//
#include <hip/hip_runtime.h>
#include <hip/hip_bf16.h>

#define BB 32
#define TT 512
#define NN 1024
#define RR 4
#define II 8
#define DT_C 0.1f

#define BPB 32
#define GRID (BB * BPB)

// fallback (round-3) tiling
#define NBLK 32
#define ROWS (NN / NBLK)
#define VBLK 16

typedef __attribute__((ext_vector_type(8))) unsigned short ushort8v;

__device__ __forceinline__ float bf2f(unsigned short u) {
    union { unsigned int ui; float f; } cv; cv.ui = ((unsigned int)u) << 16; return cv.f;
}
__device__ __forceinline__ float bf2f_lo(unsigned int u) {
    union { unsigned int ui; float f; } cv; cv.ui = u << 16; return cv.f;
}
__device__ __forceinline__ float bf2f_hi(unsigned int u) {
    union { unsigned int ui; float f; } cv; cv.ui = u & 0xffff0000u; return cv.f;
}
__device__ __forceinline__ unsigned short f2bf_rne(float x) {
    union { float f; unsigned int ui; } cv; cv.f = x;
    unsigned int u = cv.ui; u += 0x7FFFu + ((u >> 16) & 1u);
    return (unsigned short)(u >> 16);
}
__device__ __forceinline__ float wave_reduce(float v) {
    #pragma unroll
    for (int off = 32; off; off >>= 1) v += __shfl_down(v, off, 64);
    return v;
}

// ---- LLC-direct access helpers (sc0 sc1: bypass L1/L2, no cache flushes) ----
__device__ __forceinline__ uint4 llc_ld16(const void* p) {
    uint4 r;
    asm volatile("global_load_dwordx4 %0, %1, off sc0 sc1\n\ts_waitcnt vmcnt(0)"
                 : "=&v"(r) : "v"(p) : "memory");
    return r;
}
__device__ __forceinline__ float llc_ldf(const float* p) {
    float r;
    asm volatile("global_load_dword %0, %1, off sc0 sc1\n\ts_waitcnt vmcnt(0)"
                 : "=&v"(r) : "v"(p) : "memory");
    return r;
}
__device__ __forceinline__ void llc_ldf2(const float* p0, const float* p1,
                                         float& a, float& b) {
    asm volatile("global_load_dword %0, %2, off sc0 sc1\n\t"
                 "global_load_dword %1, %3, off sc0 sc1\n\t"
                 "s_waitcnt vmcnt(0)"
                 : "=&v"(a), "=&v"(b) : "v"(p0), "v"(p1) : "memory");
}
__device__ __forceinline__ void llc_stf(float* p, float v) {
    asm volatile("global_store_dword %0, %1, off sc0 sc1" :: "v"(p), "v"(v) : "memory");
}
__device__ __forceinline__ void llc_st8(float* p, float a, float b) {
    float2 v; v.x = a; v.y = b;
    asm volatile("global_store_dwordx2 %0, %1, off sc0 sc1" :: "v"(p), "v"(v) : "memory");
}

// ---------- conv: J (fp32) -> Jl register-tile layout (bf16 pairs) ----------
// dword index: ((((b*32+k)*4 + w)*64 + l)*64 + j*8 + e2)
//   lo = J[b][k*32+w*8+j][l+128*e2], hi = J[...][l+128*e2+64]
__global__ __launch_bounds__(256) void k_convJl(const float* __restrict__ J,
                                                unsigned int* __restrict__ Jl) {
    const int b = blockIdx.x >> 5, k = blockIdx.x & 31;
    const int w = threadIdx.x >> 6, l = threadIdx.x & 63;
    unsigned int* dst = Jl + ((((size_t)(b * 32 + k) * 4 + w) * 64 + l) * 64);
    #pragma unroll
    for (int j = 0; j < 8; ++j) {
        const int row = k * 32 + w * 8 + j;
        const float* __restrict__ Jrow = J + ((size_t)b * NN + row) * NN;
        unsigned int out[8];
        #pragma unroll
        for (int e2 = 0; e2 < 8; ++e2) {
            const int c0 = l + 128 * e2;
            out[e2] = (unsigned int)f2bf_rne(Jrow[c0]) |
                      ((unsigned int)f2bf_rne(Jrow[c0 + 64]) << 16);
        }
        *(uint4*)(dst + j * 8)     = make_uint4(out[0], out[1], out[2], out[3]);
        *(uint4*)(dst + j * 8 + 4) = make_uint4(out[4], out[5], out[6], out[7]);
    }
}

// ---------------- barrier (round-5 proven: relaxed + vmcnt drain) ----------------
__device__ __forceinline__ void batch_barrier(unsigned* cnt, unsigned* gen,
                                              unsigned expect) {
    asm volatile("s_waitcnt vmcnt(0) lgkmcnt(0)" ::: "memory");
    __syncthreads();
    if (threadIdx.x == 0) {
        unsigned old = __hip_atomic_fetch_add(cnt, 1u, __ATOMIC_RELAXED,
                                              __HIP_MEMORY_SCOPE_AGENT);
        if (old == BPB - 1u) {
            __hip_atomic_store(cnt, 0u, __ATOMIC_RELAXED, __HIP_MEMORY_SCOPE_AGENT);
            asm volatile("s_waitcnt vmcnt(0)" ::: "memory");
            __hip_atomic_fetch_add(gen, 1u, __ATOMIC_RELAXED, __HIP_MEMORY_SCOPE_AGENT);
        } else {
            while (__hip_atomic_load(gen, __ATOMIC_RELAXED, __HIP_MEMORY_SCOPE_AGENT)
                   < expect)
                __builtin_amdgcn_s_sleep(2);
        }
    }
    __syncthreads();
}

// ---------------- persistent kernel: J in VGPRs, V in LDS ----------------
__global__ __launch_bounds__(256, 4) void k_persist(
    const unsigned int* __restrict__ Jl,
    float* __restrict__ rbuf,     // [b][1024]
    float* __restrict__ abuf,     // [b][512]
    float* __restrict__ pa,       // [b][k][512] partial a vectors
    float* __restrict__ sqpart,   // [b][32]
    float* __restrict__ r2part,   // [b][32]
    float* __restrict__ zpart,    // [b][128] (k*4+q)
    unsigned* __restrict__ cnt, unsigned* __restrict__ gen,
    const float* __restrict__ m, const float* __restrict__ wIn,
    const float* __restrict__ inputs, const float* __restrict__ f,
    float* __restrict__ outx, float* __restrict__ outz)
{
    const int bid = blockIdx.x;
    const int b = (bid & 7) * 4 + (bid >> 8);
    const int k = (bid >> 3) & 31;
    const int tid = threadIdx.x, lane = tid & 63, wave = tid >> 6;
    const int row_loc = tid >> 3, sub = tid & 7;
    const int i_loc = k * 32 + row_loc;

    __shared__ unsigned short V_lds[32][512];   // 32 KB: this block's V rows
    __shared__ float r_sh[NN];                  // 4 KB
    __shared__ float a_sh[TT];                  // 2 KB
    __shared__ float r_next[32];
    __shared__ float Jr_sh[32];
    __shared__ float r2sh[32];
    __shared__ float zred[32][4];
    __shared__ float red4[4][16];
    __shared__ float csh[2], zsh[RR], esh[RR], ush[II];

    unsigned* mycnt = cnt + b * 32;
    unsigned* mygen = gen + b * 32;
    unsigned bar = 0;

    // ---- preamble: load J tile into registers ----
    unsigned int jreg[64];
    {
        const uint4* jp = (const uint4*)(Jl +
            ((((size_t)(b * 32 + k) * 4 + wave) * 64 + lane) * 64));
        #pragma unroll
        for (int q = 0; q < 16; ++q) {
            uint4 v = jp[q];
            jreg[q * 4] = v.x; jreg[q * 4 + 1] = v.y;
            jreg[q * 4 + 2] = v.z; jreg[q * 4 + 3] = v.w;
        }
    }
    // zero V slice
    {
        unsigned long long* vz = (unsigned long long*)&V_lds[0][0];
        for (int q = tid; q < 32 * 512 / 4; q += 256) vz[q] = 0ull;
    }
    float4 nrow = {0.f, 0.f, 0.f, 0.f};
    float xreg = 0.f;
    if (sub == 0) llc_stf(rbuf + b * NN + i_loc, 0.f);
    if (tid < 4)  llc_stf(zpart + b * 128 + k * 4 + tid, 0.f);
    if (tid == 4) llc_stf(r2part + b * 32 + k, 0.f);
    batch_barrier(mycnt, mygen, ++bar);

    for (int t = 0; t < TT; ++t) {
        // ============ phase R: reduce partial a over 32 blocks (slice of 16 s) ============
        {
            const int s_off = tid & 15, kk = tid >> 4;      // kk 0..15
            const int s = k * 16 + s_off;
            float v = 0.f;
            if (s < t) {
                float v0, v1;
                llc_ldf2(pa + ((size_t)b * 32 + kk) * TT + s,
                         pa + ((size_t)b * 32 + kk + 16) * TT + s, v0, v1);
                v = v0 + v1;
            }
            v += __shfl_down(v, 32, 64);
            v += __shfl_down(v, 16, 64);
            if ((tid & 63) < 16) red4[wave][s_off] = v;
            __syncthreads();
            if (tid < 16) {
                float a = red4[0][tid] + red4[1][tid] + red4[2][tid] + red4[3][tid];
                const int s2 = k * 16 + tid;
                float sq = 0.f;
                if (s2 < t) { llc_stf(abuf + b * TT + s2, a); sq = a * a; }
                sq += __shfl_down(sq, 8, 16);
                sq += __shfl_down(sq, 4, 16);
                sq += __shfl_down(sq, 2, 16);
                sq += __shfl_down(sq, 1, 16);
                if (tid == 0) llc_stf(sqpart + b * 32 + k, sq);
            }
        }
        batch_barrier(mycnt, mygen, ++bar);

        // ============ phase M ============
        // -- step 1: gather r, a, scalars --
        {
            union { uint4 u; float4 fv; } cv;
            cv.u = llc_ld16(rbuf + b * NN + tid * 4);
            *(float4*)&r_sh[tid * 4] = cv.fv;
        }
        if (tid < 128) {
            const int s0 = tid * 4;
            if (s0 < t) {
                union { uint4 u; float4 fv; } cv;
                cv.u = llc_ld16(abuf + b * TT + s0);
                a_sh[s0]     = cv.fv.x;
                a_sh[s0 + 1] = (s0 + 1 < t) ? cv.fv.y : 0.f;
                a_sh[s0 + 2] = (s0 + 2 < t) ? cv.fv.z : 0.f;
                a_sh[s0 + 3] = (s0 + 3 < t) ? cv.fv.w : 0.f;
            } else {
                *(float4*)&a_sh[s0] = make_float4(0.f, 0.f, 0.f, 0.f);
            }
        }
        if (wave == 0) {        // sigma = 0.1|r|^2 - |a|^2
            float v = (lane < 32) ? 0.1f * llc_ldf(r2part + b * 32 + lane)
                                  : -llc_ldf(sqpart + b * 32 + (lane - 32));
            v = wave_reduce(v);
            if (lane == 0) {
                const float c = 1.f / (1.f + v);
                csh[0] = c; csh[1] = sqrtf(c);
            }
        } else if (wave == 1) { // z = sum zparts
            float v0, v1;
            llc_ldf2(zpart + b * 128 + lane, zpart + b * 128 + 64 + lane, v0, v1);
            float v = v0 + v1;
            v += __shfl_down(v, 32, 64);
            v += __shfl_down(v, 16, 64);
            v += __shfl_down(v, 8, 64);
            v += __shfl_down(v, 4, 64);
            if (lane < RR) {
                zsh[lane] = v;
                esh[lane] = v - f[((size_t)b * TT + t) * RR + lane];
                if (k == 0) outz[((size_t)b * TT + t) * RR + lane] = v;
            }
        }
        if (tid >= 128 && tid < 128 + II)
            ush[tid - 128] = inputs[((size_t)b * TT + t) * II + (tid - 128)];
        __syncthreads();

        // -- step 2: Jr from registers; Pr partial from LDS V --
        float accJ[8] = {0.f, 0.f, 0.f, 0.f, 0.f, 0.f, 0.f, 0.f};
        #pragma unroll
        for (int e2 = 0; e2 < 8; ++e2) {
            const float rv0 = r_sh[lane + 128 * e2];
            const float rv1 = r_sh[lane + 128 * e2 + 64];
            #pragma unroll
            for (int j = 0; j < 8; ++j) {
                const unsigned int w = jreg[j * 8 + e2];
                accJ[j] = fmaf(bf2f_lo(w), rv0, accJ[j]);
                accJ[j] = fmaf(bf2f_hi(w), rv1, accJ[j]);
            }
        }
        #pragma unroll
        for (int j = 0; j < 8; ++j) {
            float v = wave_reduce(accJ[j]);
            if (lane == 0) Jr_sh[wave * 8 + j] = v;
        }

        float accp = 0.f;
        for (int mm = 0; mm * 64 < t; ++mm) {
            const int s0 = mm * 64 + sub * 8;
            const ushort8v vv = *(const ushort8v*)&V_lds[row_loc][s0];
            const float4 a0 = *(const float4*)&a_sh[s0];
            const float4 a1 = *(const float4*)&a_sh[s0 + 4];
            accp = fmaf(bf2f(vv[0]), a0.x, accp);
            accp = fmaf(bf2f(vv[1]), a0.y, accp);
            accp = fmaf(bf2f(vv[2]), a0.z, accp);
            accp = fmaf(bf2f(vv[3]), a0.w, accp);
            accp = fmaf(bf2f(vv[4]), a1.x, accp);
            accp = fmaf(bf2f(vv[5]), a1.y, accp);
            accp = fmaf(bf2f(vv[6]), a1.z, accp);
            accp = fmaf(bf2f(vv[7]), a1.w, accp);
        }
        accp += __shfl_down(accp, 4, 8);
        accp += __shfl_down(accp, 2, 8);
        accp += __shfl_down(accp, 1, 8);
        __syncthreads();

        // -- step 3: owners update row state --
        if (sub == 0) {
            const float c = csh[0], sq = csh[1];
            const float pr = 0.1f * r_sh[i_loc] - accp;
            V_lds[row_loc][t] = f2bf_rne(sq * pr);

            float accx = Jr_sh[row_loc];
            const float4 mv = *(const float4*)(m + ((size_t)b * NN + i_loc) * RR);
            accx = fmaf(mv.x, zsh[0], accx); accx = fmaf(mv.y, zsh[1], accx);
            accx = fmaf(mv.z, zsh[2], accx); accx = fmaf(mv.w, zsh[3], accx);
            const float4* __restrict__ wp =
                (const float4*)(wIn + ((size_t)b * NN + i_loc) * II);
            const float4 w0 = wp[0], w1 = wp[1];
            accx = fmaf(w0.x, ush[0], accx); accx = fmaf(w0.y, ush[1], accx);
            accx = fmaf(w0.z, ush[2], accx); accx = fmaf(w0.w, ush[3], accx);
            accx = fmaf(w1.x, ush[4], accx); accx = fmaf(w1.y, ush[5], accx);
            accx = fmaf(w1.z, ush[6], accx); accx = fmaf(w1.w, ush[7], accx);
            const float xn = (1.0f - DT_C) * xreg + DT_C * accx;
            xreg = xn;
            outx[((size_t)b * TT + t) * NN + i_loc] = xn;

            const float cpr = c * pr;
            nrow.x = fmaf(-cpr, esh[0], nrow.x);
            nrow.y = fmaf(-cpr, esh[1], nrow.y);
            nrow.z = fmaf(-cpr, esh[2], nrow.z);
            nrow.w = fmaf(-cpr, esh[3], nrow.w);

            const float rp = tanhf(xn);
            r_next[row_loc] = rp;
            r2sh[row_loc] = rp * rp;
            llc_stf(rbuf + b * NN + i_loc, rp);
            ((float4*)zred)[row_loc] = make_float4(nrow.x * rp, nrow.y * rp,
                                                   nrow.z * rp, nrow.w * rp);
        }
        __syncthreads();

        // -- step 4: block-local sums + next-step partial a --
        if (tid < 4) {
            float zp = 0.f;
            #pragma unroll
            for (int i = 0; i < 32; ++i) zp += zred[i][tid];
            llc_stf(zpart + b * 128 + k * 4 + tid, zp);
        } else if (tid == 4) {
            float r2 = 0.f;
            #pragma unroll
            for (int i = 0; i < 32; ++i) r2 += r2sh[i];
            llc_stf(r2part + b * 32 + k, r2);
        }
        if (t < TT - 1) {
            const int s0 = 2 * tid;
            if (s0 <= t) {
                float a0 = 0.f, a1 = 0.f;
                for (int i = 0; i < 32; ++i) {
                    const unsigned int vv = *(const unsigned int*)&V_lds[i][s0];
                    const float rv = r_next[i];
                    a0 = fmaf(bf2f_lo(vv), rv, a0);
                    a1 = fmaf(bf2f_hi(vv), rv, a1);
                }
                llc_st8(pa + ((size_t)b * 32 + k) * TT + s0, a0, a1);
            }
        }
        batch_barrier(mycnt, mygen, ++bar);
    }
}

// ---------------- fallback: proven round-3 path ----------------
__global__ __launch_bounds__(256) void k_convJ_old(const float* __restrict__ J,
                                                   unsigned short* __restrict__ Jp) {
    const int row = blockIdx.x;
    const int tid = threadIdx.x;
    __shared__ float rowsh[NN];
    const float4* __restrict__ src = (const float4*)(J + (size_t)row * NN);
    float4* dst4 = (float4*)rowsh;
    for (int k = tid; k < NN / 4; k += 256) dst4[k] = src[k];
    __syncthreads();
    const int o0 = tid * 4;
    unsigned short out[4];
    #pragma unroll
    for (int j = 0; j < 4; ++j) {
        const int o = o0 + j;
        const int l = (o >> 3) & 63, g = o >> 9, e = o & 7;
        out[j] = f2bf_rne(rowsh[l + 64 * (8 * g + e)]);
    }
    uint2 w;
    w.x = (unsigned int)out[0] | ((unsigned int)out[1] << 16);
    w.y = (unsigned int)out[2] | ((unsigned int)out[3] << 16);
    *(uint2*)(Jp + (size_t)row * NN + o0) = w;
}

__global__ __launch_bounds__(256) void kA_fb(
    const float* __restrict__ x, const unsigned short* __restrict__ Jp,
    const unsigned short* __restrict__ Vp, const float* __restrict__ nmat,
    float* __restrict__ r_out, float* __restrict__ a_out,
    float* __restrict__ Jr, float* __restrict__ zbuf,
    float* __restrict__ part, int t)
{
    const int b   = blockIdx.x / (NBLK + VBLK);
    const int blk = blockIdx.x % (NBLK + VBLK);
    const int tid = threadIdx.x, lane = tid & 63, wave = tid >> 6;

    __shared__ float r_sh[NN];
    __shared__ float red_sh[4];

    for (int j = tid; j < NN; j += 256) {
        const float rv = tanhf(x[b * NN + j]);
        r_sh[j] = rv;
        if (blk == 0) r_out[b * NN + j] = rv;
    }
    __syncthreads();

    if (blk < NBLK) {
        for (int rr = wave; rr < ROWS; rr += 4) {
            const int row = blk * ROWS + rr;
            const ushort8v* __restrict__ Jrow =
                (const ushort8v*)(Jp + ((size_t)b * NN + row) * NN);
            const ushort8v jv0 = Jrow[lane];
            const ushort8v jv1 = Jrow[64 + lane];
            float acc = 0.0f;
            #pragma unroll
            for (int e = 0; e < 8; ++e) acc = fmaf(bf2f(jv0[e]), r_sh[lane + 64 * e], acc);
            #pragma unroll
            for (int e = 0; e < 8; ++e) acc = fmaf(bf2f(jv1[e]), r_sh[lane + 512 + 64 * e], acc);
            acc = wave_reduce(acc);
            if (lane == 0) Jr[b * NN + row] = acc;
        }
        if (blk == 0) {
            float p = 0.0f;
            for (int j = tid; j < NN; j += 256) p = fmaf(r_sh[j], r_sh[j], p);
            p = wave_reduce(p);
            if (lane == 0) red_sh[wave] = p;
            __syncthreads();
            if (tid == 0)
                part[b * 72 + 64] = 0.1f * (red_sh[0] + red_sh[1] + red_sh[2] + red_sh[3]);
            if (wave < RR) {
                float acc = 0.0f;
                for (int i2 = lane; i2 < NN; i2 += 64)
                    acc = fmaf(nmat[((size_t)b * NN + i2) * RR + wave], r_sh[i2], acc);
                acc = wave_reduce(acc);
                if (lane == 0) zbuf[b * RR + wave] = acc;
            }
        }
    } else {
        const int wid = (blk - NBLK) * 4 + wave;
        float negsum = 0.0f;
        for (int s = wid; s < t; s += 64) {
            const ushort8v* __restrict__ col =
                (const ushort8v*)(Vp + ((size_t)b * TT + s) * NN);
            const ushort8v vv0 = col[lane];
            const ushort8v vv1 = col[64 + lane];
            float acc = 0.0f;
            #pragma unroll
            for (int e = 0; e < 8; ++e) acc = fmaf(bf2f(vv0[e]), r_sh[lane + 64 * e], acc);
            #pragma unroll
            for (int e = 0; e < 8; ++e) acc = fmaf(bf2f(vv1[e]), r_sh[lane + 512 + 64 * e], acc);
            acc = wave_reduce(acc);
            if (lane == 0) {
                a_out[b * TT + s] = acc;
                negsum = fmaf(-acc, acc, negsum);
            }
        }
        if (lane == 0) part[b * 72 + wid] = negsum;
    }
}

__global__ __launch_bounds__(256) void kB_fb(
    unsigned short* __restrict__ Vp, const float* __restrict__ r,
    const float* __restrict__ a, const float* __restrict__ Jr,
    const float* __restrict__ zbuf, const float* __restrict__ part,
    float* __restrict__ x, float* __restrict__ nmat,
    const float* __restrict__ m, const float* __restrict__ wIn,
    const float* __restrict__ inputs, const float* __restrict__ f,
    float* __restrict__ outx, float* __restrict__ outz, int t)
{
    const int b   = blockIdx.x >> 3;
    const int tb  = blockIdx.x & 7;
    const int tid = threadIdx.x;
    const int pl    = tid & 63;
    const int slice = tid >> 6;

    __shared__ float a_sh[TT];
    __shared__ float ps[4][128];
    __shared__ float zsh[RR], esh[RR], ush[II];

    for (int s = tid; s < t; s += 256) a_sh[s] = a[b * TT + s];
    if (tid < RR) {
        const float zv = zbuf[b * RR + tid];
        zsh[tid] = zv;
        esh[tid] = zv - f[((size_t)b * TT + t) * RR + tid];
    }
    if (tid >= 64 && tid < 64 + II)
        ush[tid - 64] = inputs[((size_t)b * TT + t) * II + (tid - 64)];
    __syncthreads();

    const int p0 = (tb * 64 + pl) * 2;
    const unsigned short* __restrict__ Vb = Vp + (size_t)b * TT * NN;

    const int s_begin = (t * slice) >> 2;
    const int s_end   = (t * (slice + 1)) >> 2;
    float acc0 = 0.0f, acc1 = 0.0f;
    #pragma unroll 4
    for (int s = s_begin; s < s_end; ++s) {
        const unsigned int w = *(const unsigned int*)(Vb + (size_t)s * NN + p0);
        const float av = a_sh[s];
        acc0 = fmaf(bf2f((unsigned short)(w & 0xFFFFu)), av, acc0);
        acc1 = fmaf(bf2f((unsigned short)(w >> 16)), av, acc1);
    }
    ps[slice][pl * 2]     = acc0;
    ps[slice][pl * 2 + 1] = acc1;
    __syncthreads();

    if (slice == 0) {
        const int l = (p0 >> 3) & 63, g = p0 >> 9, e = p0 & 7;
        const int i0 = l + 64 * (8 * g + e);
        const int i1 = i0 + 64;
        const float s0 = ps[0][pl * 2] + ps[1][pl * 2] + ps[2][pl * 2] + ps[3][pl * 2];
        const float s1 = ps[0][pl * 2 + 1] + ps[1][pl * 2 + 1] + ps[2][pl * 2 + 1] + ps[3][pl * 2 + 1];

        float sg = 0.0f;
        #pragma unroll
        for (int q = 0; q < 65; ++q) sg += part[b * 72 + q];
        const float c  = 1.0f / (1.0f + sg);
        const float sq = sqrtf(c);

        const float pr0 = 0.1f * r[b * NN + i0] - s0;
        const float pr1 = 0.1f * r[b * NN + i1] - s1;

        unsigned int wv = (unsigned int)f2bf_rne(sq * pr0) |
                          ((unsigned int)f2bf_rne(sq * pr1) << 16);
        *(unsigned int*)(Vp + ((size_t)b * TT + t) * NN + p0) = wv;

        #pragma unroll
        for (int which = 0; which < 2; ++which) {
            const int   i  = which ? i1 : i0;
            const float pr = which ? pr1 : pr0;
            float acc = Jr[b * NN + i];
            const float4 mv = *(const float4*)(m + ((size_t)b * NN + i) * RR);
            acc = fmaf(mv.x, zsh[0], acc); acc = fmaf(mv.y, zsh[1], acc);
            acc = fmaf(mv.z, zsh[2], acc); acc = fmaf(mv.w, zsh[3], acc);
            const float4* __restrict__ wp = (const float4*)(wIn + ((size_t)b * NN + i) * II);
            const float4 w0 = wp[0], w1 = wp[1];
            acc = fmaf(w0.x, ush[0], acc); acc = fmaf(w0.y, ush[1], acc);
            acc = fmaf(w0.z, ush[2], acc); acc = fmaf(w0.w, ush[3], acc);
            acc = fmaf(w1.x, ush[4], acc); acc = fmaf(w1.y, ush[5], acc);
            acc = fmaf(w1.z, ush[6], acc); acc = fmaf(w1.w, ush[7], acc);
            const float xo = x[b * NN + i];
            const float xn = (1.0f - DT_C) * xo + DT_C * acc;
            x[b * NN + i] = xn;
            outx[((size_t)b * TT + t) * NN + i] = xn;

            float4* __restrict__ np = (float4*)(nmat + ((size_t)b * NN + i) * RR);
            float4 nv = *np;
            const float cpr = c * pr;
            nv.x = fmaf(-cpr, esh[0], nv.x); nv.y = fmaf(-cpr, esh[1], nv.y);
            nv.z = fmaf(-cpr, esh[2], nv.z); nv.w = fmaf(-cpr, esh[3], nv.w);
            *np = nv;
        }
    }
    if (tb == 0 && tid < RR) outz[((size_t)b * TT + t) * RR + tid] = zsh[tid];
}

extern "C" void kernel_launch(void* const* d_in, const int* in_sizes, int n_in,
                              void* d_out, int out_size, void* d_ws, size_t ws_size,
                              hipStream_t stream) {
    const float* inputs = (const float*)d_in[0];
    const float* f      = (const float*)d_in[1];
    const float* J      = (const float*)d_in[2];
    const float* wIn    = (const float*)d_in[3];
    const float* m      = (const float*)d_in[4];

    float* outx = (float*)d_out;
    float* outz = outx + (size_t)BB * TT * NN;

    char* ws = (char*)d_ws;
    size_t off = 0;
    unsigned int* Jl = (unsigned int*)(ws + off);  off += (size_t)BB * NN * NN * 2; // 64MB (shared w/ fallback Jp)
    unsigned short* Jp_fb = (unsigned short*)Jl;                                     // overlay
    unsigned short* V1_fb = (unsigned short*)(ws + off); off += (size_t)BB * TT * NN * 2; // 32MB
    float* pa     = (float*)(ws + off); off += (size_t)BB * 32 * TT * 4;  // 2MB
    float* rbuf   = (float*)(ws + off); off += (size_t)BB * NN * 4;
    float* abuf   = (float*)(ws + off); off += (size_t)BB * TT * 4;
    float* sqpart = (float*)(ws + off); off += (size_t)BB * 32 * 4;
    float* r2part = (float*)(ws + off); off += (size_t)BB * 32 * 4;
    float* zpart  = (float*)(ws + off); off += (size_t)BB * 128 * 4;
    unsigned* cnt = (unsigned*)(ws + off); off += (size_t)BB * 32 * 4;
    unsigned* gen = (unsigned*)(ws + off); off += (size_t)BB * 32 * 4;
    // fallback-only
    float* x_fb   = (float*)(ws + off); off += (size_t)BB * NN * 4;
    float* nm     = (float*)(ws + off); off += (size_t)BB * NN * RR * 4;
    float* Jrb    = (float*)(ws + off); off += (size_t)BB * NN * 4;
    float* zb     = (float*)(ws + off); off += (size_t)BB * RR * 4 + 256;
    float* part72 = (float*)(ws + off); off += (size_t)BB * 72 * 4;

    hipMemsetAsync(cnt, 0, (size_t)BB * 32 * sizeof(unsigned), stream);
    hipMemsetAsync(gen, 0, (size_t)BB * 32 * sizeof(unsigned), stream);
    hipMemsetAsync(x_fb, 0, (size_t)BB * NN * sizeof(float), stream);
    hipMemsetAsync(nm,  0, (size_t)BB * NN * RR * sizeof(float), stream);

    k_convJl<<<BB * 32, 256, 0, stream>>>(J, Jl);

    void* kargs[] = {
        (void*)&Jl, (void*)&rbuf, (void*)&abuf, (void*)&pa,
        (void*)&sqpart, (void*)&r2part, (void*)&zpart,
        (void*)&cnt, (void*)&gen,
        (void*)&m, (void*)&wIn, (void*)&inputs, (void*)&f,
        (void*)&outx, (void*)&outz
    };
    hipError_t rc = hipLaunchCooperativeKernel((const void*)k_persist,
                                               dim3(GRID), dim3(256),
                                               kargs, 0, stream);
    if (rc != hipSuccess) {
        // fallback: proven round-3 path (rebuild Jp in old permuted layout)
        k_convJ_old<<<BB * NN, 256, 0, stream>>>(J, Jp_fb);
        for (int t = 0; t < TT; ++t) {
            kA_fb<<<BB * (NBLK + VBLK), 256, 0, stream>>>(x_fb, Jp_fb, V1_fb, nm,
                                                          rbuf, abuf, Jrb, zb, part72, t);
            kB_fb<<<BB * 8, 256, 0, stream>>>(V1_fb, rbuf, abuf, Jrb, zb, part72,
                                              x_fb, nm, m, wIn, inputs, f, outx, outz, t);
        }
    }
}

// Round 7
// 9476.056 us; speedup vs baseline: 1.5439x; 1.5439x over previous
//
#include <hip/hip_runtime.h>
#include <hip/hip_bf16.h>

#define BB 32
#define TT 512
#define NN 1024
#define RR 4
#define II 8
#define DT_C 0.1f

#define BPB 32
#define GRID (BB * BPB)

// fallback (round-3) tiling
#define NBLK 32
#define ROWS (NN / NBLK)
#define VBLK 16

typedef __attribute__((ext_vector_type(8))) unsigned short ushort8v;

__device__ __forceinline__ float bf2f(unsigned short u) {
    union { unsigned int ui; float f; } cv; cv.ui = ((unsigned int)u) << 16; return cv.f;
}
__device__ __forceinline__ float bf2f_lo(unsigned int u) {
    union { unsigned int ui; float f; } cv; cv.ui = u << 16; return cv.f;
}
__device__ __forceinline__ float bf2f_hi(unsigned int u) {
    union { unsigned int ui; float f; } cv; cv.ui = u & 0xffff0000u; return cv.f;
}
__device__ __forceinline__ unsigned short f2bf_rne(float x) {
    union { float f; unsigned int ui; } cv; cv.f = x;
    unsigned int u = cv.ui; u += 0x7FFFu + ((u >> 16) & 1u);
    return (unsigned short)(u >> 16);
}
__device__ __forceinline__ float wave_reduce(float v) {
    #pragma unroll
    for (int off = 32; off; off >>= 1) v += __shfl_down(v, off, 64);
    return v;
}

// ---- LLC-direct helpers (sc0 sc1: bypass L1/L2; LLC is the coherence point) ----
__device__ __forceinline__ float llc_ldf(const float* p) {
    float r;
    asm volatile("global_load_dword %0, %1, off sc0 sc1\n\ts_waitcnt vmcnt(0)"
                 : "=&v"(r) : "v"(p) : "memory");
    return r;
}
__device__ __forceinline__ void llc_stf(float* p, float v) {
    asm volatile("global_store_dword %0, %1, off sc0 sc1" :: "v"(p), "v"(v) : "memory");
}
__device__ __forceinline__ void llc_st8(float* p, float a, float b) {
    float2 v; v.x = a; v.y = b;
    asm volatile("global_store_dwordx2 %0, %1, off sc0 sc1" :: "v"(p), "v"(v) : "memory");
}

// ---------- conv: J (fp32) -> Jl register-tile layout (bf16 pairs) ----------
// dword index: ((((b*32+k)*4 + w)*64 + l)*64 + j*8 + e2)
//   lo = J[b][k*32+w*8+j][l+128*e2], hi = J[...][l+128*e2+64]
__global__ __launch_bounds__(256) void k_convJl(const float* __restrict__ J,
                                                unsigned int* __restrict__ Jl) {
    const int b = blockIdx.x >> 5, k = blockIdx.x & 31;
    const int w = threadIdx.x >> 6, l = threadIdx.x & 63;
    unsigned int* dst = Jl + ((((size_t)(b * 32 + k) * 4 + w) * 64 + l) * 64);
    #pragma unroll
    for (int j = 0; j < 8; ++j) {
        const int row = k * 32 + w * 8 + j;
        const float* __restrict__ Jrow = J + ((size_t)b * NN + row) * NN;
        unsigned int out[8];
        #pragma unroll
        for (int e2 = 0; e2 < 8; ++e2) {
            const int c0 = l + 128 * e2;
            out[e2] = (unsigned int)f2bf_rne(Jrow[c0]) |
                      ((unsigned int)f2bf_rne(Jrow[c0 + 64]) << 16);
        }
        *(uint4*)(dst + j * 8)     = make_uint4(out[0], out[1], out[2], out[3]);
        *(uint4*)(dst + j * 8 + 4) = make_uint4(out[4], out[5], out[6], out[7]);
    }
}

// ---------------- barrier: relaxed atomics + vmcnt drain + SLOW POLL ----------------
__device__ __forceinline__ void batch_barrier(unsigned* cnt, unsigned* gen,
                                              unsigned expect) {
    asm volatile("s_waitcnt vmcnt(0) lgkmcnt(0)" ::: "memory");
    __syncthreads();
    if (threadIdx.x == 0) {
        unsigned old = __hip_atomic_fetch_add(cnt, 1u, __ATOMIC_RELAXED,
                                              __HIP_MEMORY_SCOPE_AGENT);
        if (old == BPB - 1u) {
            __hip_atomic_store(cnt, 0u, __ATOMIC_RELAXED, __HIP_MEMORY_SCOPE_AGENT);
            asm volatile("s_waitcnt vmcnt(0)" ::: "memory");
            __hip_atomic_fetch_add(gen, 1u, __ATOMIC_RELAXED, __HIP_MEMORY_SCOPE_AGENT);
        } else {
            while (__hip_atomic_load(gen, __ATOMIC_RELAXED, __HIP_MEMORY_SCOPE_AGENT)
                   < expect)
                __builtin_amdgcn_s_sleep(8);   // ~0.2us poll: avoid LLC fetch storm
        }
    }
    __syncthreads();
}

// ---------------- persistent kernel: J in VGPRs, V rows in LDS ----------------
__global__ __launch_bounds__(256, 4) void k_persist(
    const unsigned int* __restrict__ Jl,
    float* __restrict__ rbuf,     // [b][1024] fp32 r (LLC)
    float* __restrict__ abuf,     // [b][512]  fp32 a (LLC)
    float* __restrict__ pa,       // [b][32][512] fp32 partial-a (LLC)
    float* __restrict__ sqpart,   // [b][32] slice sums of a^2
    float* __restrict__ zr,       // [b][128] z partials (k*4+q)
    unsigned* __restrict__ cnt, unsigned* __restrict__ gen,
    const float* __restrict__ m, const float* __restrict__ wIn,
    const float* __restrict__ inputs, const float* __restrict__ f,
    float* __restrict__ outx, float* __restrict__ outz)
{
    const int bid = blockIdx.x;
    const int b = (bid & 7) * 4 + (bid >> 8);
    const int k = (bid >> 3) & 31;
    const int tid = threadIdx.x, lane = tid & 63, wave = tid >> 6;
    const int row_loc = tid >> 3, sub = tid & 7;
    const int i_loc = k * 32 + row_loc;

    __shared__ unsigned short V_lds[32][512];   // 32 KB this block's V rows
    __shared__ float r_sh[NN];                  // 4 KB
    __shared__ float a_sh[2 * TT / 2 + 512];    // 2 KB: R-phase scratch, then a
    __shared__ float sq32[32];
    __shared__ float r_next[32];
    __shared__ float Jr_sh[32];
    __shared__ float zred[32][4];
    __shared__ float zr2[128];
    __shared__ float red_sg[4];
    __shared__ float fsh[RR], ush[II], csh[2], zsh[RR], esh[RR];

    unsigned* mycnt = cnt + b * 32;
    unsigned* mygen = gen + b * 32;
    unsigned bar = 0;

    // preamble: J tile -> registers (plain cached loads, once)
    unsigned int jreg[64];
    {
        const uint4* jp = (const uint4*)(Jl +
            ((((size_t)(b * 32 + k) * 4 + wave) * 64 + lane) * 64));
        #pragma unroll
        for (int q = 0; q < 16; ++q) {
            uint4 v = jp[q];
            jreg[q * 4] = v.x; jreg[q * 4 + 1] = v.y;
            jreg[q * 4 + 2] = v.z; jreg[q * 4 + 3] = v.w;
        }
    }
    {   // zero V slice
        unsigned long long* vz = (unsigned long long*)&V_lds[0][0];
        for (int q = tid; q < 32 * 512 / 4; q += 256) vz[q] = 0ull;
    }
    float4 nrow = {0.f, 0.f, 0.f, 0.f};
    float xreg = 0.f;
    if (sub == 0) llc_stf(rbuf + b * NN + i_loc, 0.f);
    if (tid < 4)  llc_stf(zr + b * 128 + k * 4 + tid, 0.f);
    batch_barrier(mycnt, mygen, ++bar);

    for (int t = 0; t < TT; ++t) {
        // ========== phase R: batched loads + slice-reduce pa -> a ==========
        float4 rqf; float2 paw; float zrw;
        {
            const float* rp  = rbuf + b * NN + tid * 4;
            const float* pap = pa + ((size_t)b * 32 + (tid >> 3)) * TT
                                  + k * 16 + (tid & 7) * 2;
            const float* zp  = zr + b * 128 + (tid & 127);
            asm volatile(
                "global_load_dwordx4 %0, %3, off sc0 sc1\n\t"
                "global_load_dwordx2 %1, %4, off sc0 sc1\n\t"
                "global_load_dword   %2, %5, off sc0 sc1\n\t"
                "s_waitcnt vmcnt(0)"
                : "=&v"(rqf), "=&v"(paw), "=&v"(zrw)
                : "v"(rp), "v"(pap), "v"(zp)
                : "memory");
        }
        *(float4*)&r_sh[tid * 4] = rqf;
        zr2[tid & 127] = zrw;                 // two writers, same value
        {
            const int s0g = k * 16 + (tid & 7) * 2;
            a_sh[tid]       = (s0g     < t) ? paw.x : 0.f;   // scratch role
            a_sh[256 + tid] = (s0g + 1 < t) ? paw.y : 0.f;
        }
        if (tid >= 136 && tid < 140) fsh[tid - 136] = f[((size_t)b * TT + t) * RR + (tid - 136)];
        if (tid >= 144 && tid < 152) ush[tid - 144] = inputs[((size_t)b * TT + t) * II + (tid - 144)];
        __syncthreads();
        if (tid < 8) {
            float A = 0.f, B = 0.f;
            #pragma unroll
            for (int kk = 0; kk < 32; ++kk) {
                A += a_sh[kk * 8 + tid];
                B += a_sh[256 + kk * 8 + tid];
            }
            llc_st8(abuf + b * TT + k * 16 + 2 * tid, A, B);
            float sq = A * A + B * B;
            sq += __shfl_down(sq, 4, 8);
            sq += __shfl_down(sq, 2, 8);
            sq += __shfl_down(sq, 1, 8);
            if (tid == 0) llc_stf(sqpart + b * 32 + k, sq);
        }
        batch_barrier(mycnt, mygen, ++bar);

        // ========== phase M ==========
        {   // a gather (one 8B LLC load per thread)
            float2 apw;
            const float* ap = abuf + b * TT + tid * 2;
            asm volatile("global_load_dwordx2 %0, %1, off sc0 sc1\n\ts_waitcnt vmcnt(0)"
                         : "=&v"(apw) : "v"(ap) : "memory");
            a_sh[2 * tid]     = apw.x;
            a_sh[2 * tid + 1] = apw.y;
        }
        {   // 0.1*|r|^2 local partials (r still in registers)
            float sqr = 0.1f * (rqf.x * rqf.x + rqf.y * rqf.y +
                                rqf.z * rqf.z + rqf.w * rqf.w);
            sqr = wave_reduce(sqr);
            if (lane == 0) red_sg[wave] = sqr;
        }
        if (wave == 0 && lane < 32) sq32[lane] = llc_ldf(sqpart + b * 32 + lane);
        __syncthreads();

        // Jr = J @ r from registers
        float accJ[8] = {0.f, 0.f, 0.f, 0.f, 0.f, 0.f, 0.f, 0.f};
        #pragma unroll
        for (int e2 = 0; e2 < 8; ++e2) {
            const float rv0 = r_sh[lane + 128 * e2];
            const float rv1 = r_sh[lane + 128 * e2 + 64];
            #pragma unroll
            for (int j = 0; j < 8; ++j) {
                const unsigned int w = jreg[j * 8 + e2];
                accJ[j] = fmaf(bf2f_lo(w), rv0, accJ[j]);
                accJ[j] = fmaf(bf2f_hi(w), rv1, accJ[j]);
            }
        }
        #pragma unroll
        for (int j = 0; j < 8; ++j) {
            float v = wave_reduce(accJ[j]);
            if (lane == 0) Jr_sh[wave * 8 + j] = v;
        }

        if (tid == 0) {
            float sg = red_sg[0] + red_sg[1] + red_sg[2] + red_sg[3];
            float sa = 0.f;
            #pragma unroll
            for (int q = 0; q < 32; ++q) sa += sq32[q];
            const float c = 1.f / (1.f + (sg - sa));
            csh[0] = c; csh[1] = sqrtf(c);
        }
        if (tid < 4) {
            float zq = 0.f;
            #pragma unroll
            for (int kk = 0; kk < 32; ++kk) zq += zr2[kk * 4 + tid];
            zsh[tid] = zq;
            esh[tid] = zq - fsh[tid];
        }
        __syncthreads();

        // Pr partial: this block's V rows x a
        float accp = 0.f;
        for (int mm = 0; mm * 64 < t; ++mm) {
            const int s0 = mm * 64 + sub * 8;
            const ushort8v vv = *(const ushort8v*)&V_lds[row_loc][s0];
            const float4 a0 = *(const float4*)&a_sh[s0];
            const float4 a1 = *(const float4*)&a_sh[s0 + 4];
            accp = fmaf(bf2f(vv[0]), a0.x, accp);
            accp = fmaf(bf2f(vv[1]), a0.y, accp);
            accp = fmaf(bf2f(vv[2]), a0.z, accp);
            accp = fmaf(bf2f(vv[3]), a0.w, accp);
            accp = fmaf(bf2f(vv[4]), a1.x, accp);
            accp = fmaf(bf2f(vv[5]), a1.y, accp);
            accp = fmaf(bf2f(vv[6]), a1.z, accp);
            accp = fmaf(bf2f(vv[7]), a1.w, accp);
        }
        accp += __shfl_down(accp, 4, 8);
        accp += __shfl_down(accp, 2, 8);
        accp += __shfl_down(accp, 1, 8);

        if (sub == 0) {
            const float c = csh[0], sqc = csh[1];
            const float pr = 0.1f * r_sh[i_loc] - accp;
            V_lds[row_loc][t] = f2bf_rne(sqc * pr);

            float accx = Jr_sh[row_loc];
            const float4 mv = *(const float4*)(m + ((size_t)b * NN + i_loc) * RR);
            accx = fmaf(mv.x, zsh[0], accx); accx = fmaf(mv.y, zsh[1], accx);
            accx = fmaf(mv.z, zsh[2], accx); accx = fmaf(mv.w, zsh[3], accx);
            const float4* __restrict__ wp =
                (const float4*)(wIn + ((size_t)b * NN + i_loc) * II);
            const float4 w0 = wp[0], w1 = wp[1];
            accx = fmaf(w0.x, ush[0], accx); accx = fmaf(w0.y, ush[1], accx);
            accx = fmaf(w0.z, ush[2], accx); accx = fmaf(w0.w, ush[3], accx);
            accx = fmaf(w1.x, ush[4], accx); accx = fmaf(w1.y, ush[5], accx);
            accx = fmaf(w1.z, ush[6], accx); accx = fmaf(w1.w, ush[7], accx);
            const float xn = (1.0f - DT_C) * xreg + DT_C * accx;
            xreg = xn;
            outx[((size_t)b * TT + t) * NN + i_loc] = xn;

            const float cpr = c * pr;
            nrow.x = fmaf(-cpr, esh[0], nrow.x);
            nrow.y = fmaf(-cpr, esh[1], nrow.y);
            nrow.z = fmaf(-cpr, esh[2], nrow.z);
            nrow.w = fmaf(-cpr, esh[3], nrow.w);

            const float rp2 = tanhf(xn);
            r_next[row_loc] = rp2;
            llc_stf(rbuf + b * NN + i_loc, rp2);
            ((float4*)zred)[row_loc] = make_float4(nrow.x * rp2, nrow.y * rp2,
                                                   nrow.z * rp2, nrow.w * rp2);
        }
        __syncthreads();

        // next-step partial a from local V rows (incl. new column t)
        if (t < TT - 1 && 2 * tid <= t) {
            const int s0 = 2 * tid;
            float A0 = 0.f, A1 = 0.f;
            #pragma unroll 8
            for (int i = 0; i < 32; ++i) {
                const unsigned vv = *(const unsigned*)&V_lds[i][s0];
                const float rv = r_next[i];
                A0 = fmaf(bf2f_lo(vv), rv, A0);
                A1 = fmaf(bf2f_hi(vv), rv, A1);
            }
            llc_st8(pa + ((size_t)b * 32 + k) * TT + s0, A0, A1);
        }
        if (tid < 4) {
            float zp = 0.f;
            #pragma unroll
            for (int i = 0; i < 32; ++i) zp += zred[i][tid];
            llc_stf(zr + b * 128 + k * 4 + tid, zp);
            if (k == 0) outz[((size_t)b * TT + t) * RR + tid] = zsh[tid];
        }
        batch_barrier(mycnt, mygen, ++bar);
    }
}

// ---------------- fallback: proven round-3 path ----------------
__global__ __launch_bounds__(256) void k_convJ_old(const float* __restrict__ J,
                                                   unsigned short* __restrict__ Jp) {
    const int row = blockIdx.x;
    const int tid = threadIdx.x;
    __shared__ float rowsh[NN];
    const float4* __restrict__ src = (const float4*)(J + (size_t)row * NN);
    float4* dst4 = (float4*)rowsh;
    for (int k = tid; k < NN / 4; k += 256) dst4[k] = src[k];
    __syncthreads();
    const int o0 = tid * 4;
    unsigned short out[4];
    #pragma unroll
    for (int j = 0; j < 4; ++j) {
        const int o = o0 + j;
        const int l = (o >> 3) & 63, g = o >> 9, e = o & 7;
        out[j] = f2bf_rne(rowsh[l + 64 * (8 * g + e)]);
    }
    uint2 w;
    w.x = (unsigned int)out[0] | ((unsigned int)out[1] << 16);
    w.y = (unsigned int)out[2] | ((unsigned int)out[3] << 16);
    *(uint2*)(Jp + (size_t)row * NN + o0) = w;
}

__global__ __launch_bounds__(256) void kA_fb(
    const float* __restrict__ x, const unsigned short* __restrict__ Jp,
    const unsigned short* __restrict__ Vp, const float* __restrict__ nmat,
    float* __restrict__ r_out, float* __restrict__ a_out,
    float* __restrict__ Jr, float* __restrict__ zbuf,
    float* __restrict__ part, int t)
{
    const int b   = blockIdx.x / (NBLK + VBLK);
    const int blk = blockIdx.x % (NBLK + VBLK);
    const int tid = threadIdx.x, lane = tid & 63, wave = tid >> 6;

    __shared__ float r_sh[NN];
    __shared__ float red_sh[4];

    for (int j = tid; j < NN; j += 256) {
        const float rv = tanhf(x[b * NN + j]);
        r_sh[j] = rv;
        if (blk == 0) r_out[b * NN + j] = rv;
    }
    __syncthreads();

    if (blk < NBLK) {
        for (int rr = wave; rr < ROWS; rr += 4) {
            const int row = blk * ROWS + rr;
            const ushort8v* __restrict__ Jrow =
                (const ushort8v*)(Jp + ((size_t)b * NN + row) * NN);
            const ushort8v jv0 = Jrow[lane];
            const ushort8v jv1 = Jrow[64 + lane];
            float acc = 0.0f;
            #pragma unroll
            for (int e = 0; e < 8; ++e) acc = fmaf(bf2f(jv0[e]), r_sh[lane + 64 * e], acc);
            #pragma unroll
            for (int e = 0; e < 8; ++e) acc = fmaf(bf2f(jv1[e]), r_sh[lane + 512 + 64 * e], acc);
            acc = wave_reduce(acc);
            if (lane == 0) Jr[b * NN + row] = acc;
        }
        if (blk == 0) {
            float p = 0.0f;
            for (int j = tid; j < NN; j += 256) p = fmaf(r_sh[j], r_sh[j], p);
            p = wave_reduce(p);
            if (lane == 0) red_sh[wave] = p;
            __syncthreads();
            if (tid == 0)
                part[b * 72 + 64] = 0.1f * (red_sh[0] + red_sh[1] + red_sh[2] + red_sh[3]);
            if (wave < RR) {
                float acc = 0.0f;
                for (int i2 = lane; i2 < NN; i2 += 64)
                    acc = fmaf(nmat[((size_t)b * NN + i2) * RR + wave], r_sh[i2], acc);
                acc = wave_reduce(acc);
                if (lane == 0) zbuf[b * RR + wave] = acc;
            }
        }
    } else {
        const int wid = (blk - NBLK) * 4 + wave;
        float negsum = 0.0f;
        for (int s = wid; s < t; s += 64) {
            const ushort8v* __restrict__ col =
                (const ushort8v*)(Vp + ((size_t)b * TT + s) * NN);
            const ushort8v vv0 = col[lane];
            const ushort8v vv1 = col[64 + lane];
            float acc = 0.0f;
            #pragma unroll
            for (int e = 0; e < 8; ++e) acc = fmaf(bf2f(vv0[e]), r_sh[lane + 64 * e], acc);
            #pragma unroll
            for (int e = 0; e < 8; ++e) acc = fmaf(bf2f(vv1[e]), r_sh[lane + 512 + 64 * e], acc);
            acc = wave_reduce(acc);
            if (lane == 0) {
                a_out[b * TT + s] = acc;
                negsum = fmaf(-acc, acc, negsum);
            }
        }
        if (lane == 0) part[b * 72 + wid] = negsum;
    }
}

__global__ __launch_bounds__(256) void kB_fb(
    unsigned short* __restrict__ Vp, const float* __restrict__ r,
    const float* __restrict__ a, const float* __restrict__ Jr,
    const float* __restrict__ zbuf, const float* __restrict__ part,
    float* __restrict__ x, float* __restrict__ nmat,
    const float* __restrict__ m, const float* __restrict__ wIn,
    const float* __restrict__ inputs, const float* __restrict__ f,
    float* __restrict__ outx, float* __restrict__ outz, int t)
{
    const int b   = blockIdx.x >> 3;
    const int tb  = blockIdx.x & 7;
    const int tid = threadIdx.x;
    const int pl    = tid & 63;
    const int slice = tid >> 6;

    __shared__ float a_sh[TT];
    __shared__ float ps[4][128];
    __shared__ float zsh[RR], esh[RR], ush[II];

    for (int s = tid; s < t; s += 256) a_sh[s] = a[b * TT + s];
    if (tid < RR) {
        const float zv = zbuf[b * RR + tid];
        zsh[tid] = zv;
        esh[tid] = zv - f[((size_t)b * TT + t) * RR + tid];
    }
    if (tid >= 64 && tid < 64 + II)
        ush[tid - 64] = inputs[((size_t)b * TT + t) * II + (tid - 64)];
    __syncthreads();

    const int p0 = (tb * 64 + pl) * 2;
    const unsigned short* __restrict__ Vb = Vp + (size_t)b * TT * NN;

    const int s_begin = (t * slice) >> 2;
    const int s_end   = (t * (slice + 1)) >> 2;
    float acc0 = 0.0f, acc1 = 0.0f;
    #pragma unroll 4
    for (int s = s_begin; s < s_end; ++s) {
        const unsigned int w = *(const unsigned int*)(Vb + (size_t)s * NN + p0);
        const float av = a_sh[s];
        acc0 = fmaf(bf2f((unsigned short)(w & 0xFFFFu)), av, acc0);
        acc1 = fmaf(bf2f((unsigned short)(w >> 16)), av, acc1);
    }
    ps[slice][pl * 2]     = acc0;
    ps[slice][pl * 2 + 1] = acc1;
    __syncthreads();

    if (slice == 0) {
        const int l = (p0 >> 3) & 63, g = p0 >> 9, e = p0 & 7;
        const int i0 = l + 64 * (8 * g + e);
        const int i1 = i0 + 64;
        const float s0 = ps[0][pl * 2] + ps[1][pl * 2] + ps[2][pl * 2] + ps[3][pl * 2];
        const float s1 = ps[0][pl * 2 + 1] + ps[1][pl * 2 + 1] + ps[2][pl * 2 + 1] + ps[3][pl * 2 + 1];

        float sg = 0.0f;
        #pragma unroll
        for (int q = 0; q < 65; ++q) sg += part[b * 72 + q];
        const float c  = 1.0f / (1.0f + sg);
        const float sq = sqrtf(c);

        const float pr0 = 0.1f * r[b * NN + i0] - s0;
        const float pr1 = 0.1f * r[b * NN + i1] - s1;

        unsigned int wv = (unsigned int)f2bf_rne(sq * pr0) |
                          ((unsigned int)f2bf_rne(sq * pr1) << 16);
        *(unsigned int*)(Vp + ((size_t)b * TT + t) * NN + p0) = wv;

        #pragma unroll
        for (int which = 0; which < 2; ++which) {
            const int   i  = which ? i1 : i0;
            const float pr = which ? pr1 : pr0;
            float acc = Jr[b * NN + i];
            const float4 mv = *(const float4*)(m + ((size_t)b * NN + i) * RR);
            acc = fmaf(mv.x, zsh[0], acc); acc = fmaf(mv.y, zsh[1], acc);
            acc = fmaf(mv.z, zsh[2], acc); acc = fmaf(mv.w, zsh[3], acc);
            const float4* __restrict__ wp = (const float4*)(wIn + ((size_t)b * NN + i) * II);
            const float4 w0 = wp[0], w1 = wp[1];
            acc = fmaf(w0.x, ush[0], acc); acc = fmaf(w0.y, ush[1], acc);
            acc = fmaf(w0.z, ush[2], acc); acc = fmaf(w0.w, ush[3], acc);
            acc = fmaf(w1.x, ush[4], acc); acc = fmaf(w1.y, ush[5], acc);
            acc = fmaf(w1.z, ush[6], acc); acc = fmaf(w1.w, ush[7], acc);
            const float xo = x[b * NN + i];
            const float xn = (1.0f - DT_C) * xo + DT_C * acc;
            x[b * NN + i] = xn;
            outx[((size_t)b * TT + t) * NN + i] = xn;

            float4* __restrict__ np = (float4*)(nmat + ((size_t)b * NN + i) * RR);
            float4 nv = *np;
            const float cpr = c * pr;
            nv.x = fmaf(-cpr, esh[0], nv.x); nv.y = fmaf(-cpr, esh[1], nv.y);
            nv.z = fmaf(-cpr, esh[2], nv.z); nv.w = fmaf(-cpr, esh[3], nv.w);
            *np = nv;
        }
    }
    if (tb == 0 && tid < RR) outz[((size_t)b * TT + t) * RR + tid] = zsh[tid];
}

extern "C" void kernel_launch(void* const* d_in, const int* in_sizes, int n_in,
                              void* d_out, int out_size, void* d_ws, size_t ws_size,
                              hipStream_t stream) {
    const float* inputs = (const float*)d_in[0];
    const float* f      = (const float*)d_in[1];
    const float* J      = (const float*)d_in[2];
    const float* wIn    = (const float*)d_in[3];
    const float* m      = (const float*)d_in[4];

    float* outx = (float*)d_out;
    float* outz = outx + (size_t)BB * TT * NN;

    char* ws = (char*)d_ws;
    size_t off = 0;
    unsigned int* Jl = (unsigned int*)(ws + off);  off += (size_t)BB * NN * NN * 2; // 64MB
    unsigned short* Jp_fb = (unsigned short*)Jl;                                     // overlay
    unsigned short* V1_fb = (unsigned short*)(ws + off); off += (size_t)BB * TT * NN * 2; // 32MB
    float* pa     = (float*)(ws + off); off += (size_t)BB * 32 * TT * 4;  // 2MB
    float* rbuf   = (float*)(ws + off); off += (size_t)BB * NN * 4;
    float* abuf   = (float*)(ws + off); off += (size_t)BB * TT * 4;
    float* sqpart = (float*)(ws + off); off += (size_t)BB * 32 * 4;
    float* zrp    = (float*)(ws + off); off += (size_t)BB * 128 * 4;
    unsigned* cnt = (unsigned*)(ws + off); off += (size_t)BB * 32 * 4;
    unsigned* gen = (unsigned*)(ws + off); off += (size_t)BB * 32 * 4;
    // fallback-only
    float* x_fb   = (float*)(ws + off); off += (size_t)BB * NN * 4;
    float* nm     = (float*)(ws + off); off += (size_t)BB * NN * RR * 4;
    float* Jrb    = (float*)(ws + off); off += (size_t)BB * NN * 4;
    float* zb     = (float*)(ws + off); off += (size_t)BB * RR * 4 + 256;
    float* part72 = (float*)(ws + off); off += (size_t)BB * 72 * 4;

    hipMemsetAsync(cnt, 0, (size_t)BB * 32 * sizeof(unsigned), stream);
    hipMemsetAsync(gen, 0, (size_t)BB * 32 * sizeof(unsigned), stream);
    hipMemsetAsync(x_fb, 0, (size_t)BB * NN * sizeof(float), stream);
    hipMemsetAsync(nm,  0, (size_t)BB * NN * RR * sizeof(float), stream);

    k_convJl<<<BB * 32, 256, 0, stream>>>(J, Jl);

    void* kargs[] = {
        (void*)&Jl, (void*)&rbuf, (void*)&abuf, (void*)&pa,
        (void*)&sqpart, (void*)&zrp,
        (void*)&cnt, (void*)&gen,
        (void*)&m, (void*)&wIn, (void*)&inputs, (void*)&f,
        (void*)&outx, (void*)&outz
    };
    hipError_t rc = hipLaunchCooperativeKernel((const void*)k_persist,
                                               dim3(GRID), dim3(256),
                                               kargs, 0, stream);
    if (rc != hipSuccess) {
        k_convJ_old<<<BB * NN, 256, 0, stream>>>(J, Jp_fb);
        for (int t = 0; t < TT; ++t) {
            kA_fb<<<BB * (NBLK + VBLK), 256, 0, stream>>>(x_fb, Jp_fb, V1_fb, nm,
                                                          rbuf, abuf, Jrb, zb, part72, t);
            kB_fb<<<BB * 8, 256, 0, stream>>>(V1_fb, rbuf, abuf, Jrb, zb, part72,
                                              x_fb, nm, m, wIn, inputs, f, outx, outz, t);
        }
    }
}